// Round 3
// baseline (175.870 us; speedup 1.0000x reference)
//
#include <hip/hip_runtime.h>
#include <hip/hip_bf16.h>
#include <math.h>

#define LN2_F 0.69314718055994531f

typedef _Float16 half8 __attribute__((ext_vector_type(8)));  // 8 f16 = 4 VGPRs (MFMA A/B frag)
typedef _Float16 h4_t __attribute__((ext_vector_type(4)));   // 4 f16 = 2 VGPRs (b64 / tr-read)
typedef __fp16 pk2_t __attribute__((ext_vector_type(2)));    // cvt_pkrtz native result type
typedef __attribute__((ext_vector_type(4))) float f32x4;     // MFMA C/D frag
typedef __attribute__((ext_vector_type(8))) short short8;

// ---------------- weight prep: fp32 W -> f16 in B-fragment order ----------------
// Fragment layout for mfma_f32_16x16x32_f16:
//   B: lane l holds B[k = s*32 + (l>>4)*8 + j][n = ct*16 + (l&15)], j=0..7
// ws layout (shorts): chunk cp = s*NT + ct occupies 512 shorts at [cp*512 + lane*8 + j].
// Layer bases (shorts): L0=0 (64x128,CP16), L1=8192 (128x128,CP32), L2=24576 (128x64,CP16),
// L3=32768 (64x32,CP4). Total 34816 shorts = 69632 B.
__global__ void prep_weights(const float* __restrict__ W0, const float* __restrict__ W1,
                             const float* __restrict__ W2, const float* __restrict__ W3,
                             short* __restrict__ ws) {
    int e = blockIdx.x * 256 + threadIdx.x;     // unit id, 4352 total
    const float* W; int N, NT, base, ul;
    if (e < 1024)      { W = W0; N = 128; NT = 8; base = 0;     ul = e; }
    else if (e < 3072) { W = W1; N = 128; NT = 8; base = 8192;  ul = e - 1024; }
    else if (e < 4096) { W = W2; N = 64;  NT = 4; base = 24576; ul = e - 3072; }
    else if (e < 4352) { W = W3; N = 32;  NT = 2; base = 32768; ul = e - 4096; }
    else return;
    const int cp = ul >> 6, lane = ul & 63;
    const int s = cp / NT, ct = cp % NT;
    const int k0 = s * 32 + (lane >> 4) * 8;
    const int n = ct * 16 + (lane & 15);
    union { half8 h; short8 s; } v;
#pragma unroll
    for (int j = 0; j < 8; ++j) v.h[j] = (_Float16)W[(size_t)(k0 + j) * N + n];
    *(short8*)(ws + base + cp * 512 + lane * 8) = v.s;
}

// ---------------- activation LDS layout (per wave, per 16-row m-tile) ----------------
// Subtiled for ds_read_b64_tr_b16: element (row, k) lives at half-index
//     (k>>2)*64 + (k&3)*16 + row          (region = 32 blocks x 64 halfs = 2048 halfs)
// Store side: lane (q,m) owns D rows q*4..q*4+3 of col ct*16+m -> ONE ds_write_b64
//     at (ct*4 + (m>>2))*64 + (m&3)*16 + q*4.
// Read side (A-frag, slice s): lane (q,m) supplies byte addr base + (s*8+2q)*128 + m*8;
// the 16-lane-group gather of ds_read_b64_tr_b16 delivers elem j = A[m][s*32+q*8+j]
// (j=0..3; offset:128 gives j=4..7).
#define REGION_HALFS 2048

__device__ __forceinline__ void lds_fence() {
    asm volatile("s_waitcnt lgkmcnt(0)" ::: "memory");
}

template <int K>
__device__ __forceinline__ void load_a_tr(const _Float16* region, unsigned lane_off,
                                          half8 af[4]) {
    const unsigned base = (unsigned)(uintptr_t)region + lane_off;
#pragma unroll
    for (int s = 0; s < K / 32; ++s) {
        h4_t lo, hi;
        asm volatile("ds_read_b64_tr_b16 %0, %2\n\t"
                     "ds_read_b64_tr_b16 %1, %2 offset:128"
                     : "=&v"(lo), "=&v"(hi)
                     : "v"(base + (unsigned)(s * 1024))
                     : "memory");
        af[s] = __builtin_shufflevector(lo, hi, 0, 1, 2, 3, 4, 5, 6, 7);
    }
}

template <int N>
__device__ __forceinline__ void store_d_tr(_Float16* __restrict__ region, int m, int q,
                                           const f32x4* acc, bool relu) {
    const int base = (m >> 2) * 64 + (m & 3) * 16 + q * 4;
#pragma unroll
    for (int ct = 0; ct < N / 16; ++ct) {
        f32x4 v = acc[ct];
        float a0 = relu ? fmaxf(v[0], 0.0f) : v[0];
        float a1 = relu ? fmaxf(v[1], 0.0f) : v[1];
        float a2 = relu ? fmaxf(v[2], 0.0f) : v[2];
        float a3 = relu ? fmaxf(v[3], 0.0f) : v[3];
        pk2_t p0 = __builtin_amdgcn_cvt_pkrtz(a0, a1);
        pk2_t p1 = __builtin_amdgcn_cvt_pkrtz(a2, a3);
        h4_t h = {(_Float16)p0[0], (_Float16)p0[1], (_Float16)p1[0], (_Float16)p1[1]};
        *(h4_t*)(region + ct * 256 + base) = h;       // ds_write_b64
    }
}

// ---------------- per-wave layer compute: 2 m-tiles share every B fragment ----------------
// B-fragments stream from GLOBAL (L2-resident): keeps vmem pipe busy, LDS pipe free.
// ba = preloaded s=0 fragments; explicit distance-1 double-buffer hides L2 latency.
template <int NT>
__device__ __forceinline__ void preload_b(const half8* __restrict__ wf, int lane,
                                          half8 (&b)[8]) {
#pragma unroll
    for (int ct = 0; ct < NT; ++ct) b[ct] = wf[ct * 64 + lane];
}

template <int K, int N>
__device__ __forceinline__ void layer_frag2(const half8* __restrict__ wf,
                                            const float* bias,
                                            const half8 (&af)[2][4], int lane,
                                            f32x4 (&acc)[2][8],
                                            half8 (&ba)[8], half8 (&bb)[8]) {
    constexpr int NK = K / 32, NT = N / 16;
#pragma unroll
    for (int ct = 0; ct < NT; ++ct) {
        float b = bias[ct];
        acc[0][ct] = f32x4{b, b, b, b};
        acc[1][ct] = f32x4{b, b, b, b};
    }
#pragma unroll
    for (int s = 0; s < NK; ++s) {
        half8 (&bc)[8] = (s & 1) ? bb : ba;
        half8 (&bn)[8] = (s & 1) ? ba : bb;
        if (s + 1 < NK) {
#pragma unroll
            for (int ct = 0; ct < NT; ++ct) bn[ct] = wf[((s + 1) * NT + ct) * 64 + lane];
        }
#pragma unroll
        for (int ct = 0; ct < NT; ++ct) {
            acc[0][ct] = __builtin_amdgcn_mfma_f32_16x16x32_f16(af[0][s], bc[ct], acc[0][ct], 0, 0, 0);
            acc[1][ct] = __builtin_amdgcn_mfma_f32_16x16x32_f16(af[1][s], bc[ct], acc[1][ct], 0, 0, 0);
        }
    }
}

__global__ __launch_bounds__(256, 4) void mlp_phi_mfma(
    const float* __restrict__ u,
    const float* __restrict__ b0, const float* __restrict__ b1,
    const float* __restrict__ b2, const float* __restrict__ b3,
    const short* __restrict__ ws,
    const float* __restrict__ var1, const float* __restrict__ var2,
    const float* __restrict__ var3, const float* __restrict__ var4,
    const float* __restrict__ var5, const float* __restrict__ var6,
    float* __restrict__ out) {
    // 4 waves/block, each wave owns 32 rows (two 16-row m-tiles) end-to-end.
    // No __syncthreads anywhere. LDS: 4 waves x 2 regions x 2048 halfs = 32768 B
    // -> up to 5 blocks/CU by LDS (vs 34816B padded layout before).
    __shared__ __align__(16) _Float16 lds[4 * 2 * REGION_HALFS];
    const int t = threadIdx.x, lane = t & 63, wave = t >> 6;
    const int m = lane & 15, q = lane >> 4;
    _Float16* lw = lds + wave * 2 * REGION_HALFS;
    const unsigned lane_rd = (unsigned)(q * 256 + m * 8);   // tr-read per-lane byte offset
    const size_t row0 = (size_t)blockIdx.x * 128 + wave * 32;

    const half8* wf0 = (const half8*)(ws);
    const half8* wf1 = (const half8*)(ws + 8192);
    const half8* wf2 = (const half8*)(ws + 24576);
    const half8* wf3 = (const half8*)(ws + 32768);

    // ---- hoist biases + epilogue constants into registers ----
    float bb0v[8], bb1v[8], bb2v[4], bb3v[2];
#pragma unroll
    for (int ct = 0; ct < 8; ++ct) bb0v[ct] = b0[ct * 16 + m];
#pragma unroll
    for (int ct = 0; ct < 8; ++ct) bb1v[ct] = b1[ct * 16 + m];
#pragma unroll
    for (int ct = 0; ct < 4; ++ct) bb2v[ct] = b2[ct * 16 + m];
#pragma unroll
    for (int ct = 0; ct < 2; ++ct) bb3v[ct] = b3[ct * 16 + m];

    float ev1[2], ev2[2], ev4[2], ev6[2], ev5h[2], ec3[2];
#pragma unroll
    for (int ot = 0; ot < 2; ++ot) {
        const int d = ot * 16 + m;
        ev1[ot] = var1[d]; ev2[ot] = var2[d]; ev4[ot] = var4[d]; ev6[ot] = var6[d];
        ev5h[ot] = 0.5f * var5[d];
        ec3[ot] = var3[d] - ev4[ot] - ev5h[ot];     // li coefficient, hoisted
    }

    half8 af[2][4];
    f32x4 acc[2][8];
    half8 ba[8], bb[8];

    // ---- Layer 0 (64 -> 128): A straight from global u, cvt_pkrtz fp32->f16 ----
#pragma unroll
    for (int mt = 0; mt < 2; ++mt) {
        const float* up = u + (row0 + mt * 16 + m) * 64;
#pragma unroll
        for (int s = 0; s < 2; ++s) {
            float4 v0 = *(const float4*)(up + s * 32 + q * 8);
            float4 v1 = *(const float4*)(up + s * 32 + q * 8 + 4);
            pk2_t p0 = __builtin_amdgcn_cvt_pkrtz(v0.x, v0.y);
            pk2_t p1 = __builtin_amdgcn_cvt_pkrtz(v0.z, v0.w);
            pk2_t p2 = __builtin_amdgcn_cvt_pkrtz(v1.x, v1.y);
            pk2_t p3 = __builtin_amdgcn_cvt_pkrtz(v1.z, v1.w);
            af[mt][s] = half8{(_Float16)p0[0], (_Float16)p0[1], (_Float16)p1[0], (_Float16)p1[1],
                              (_Float16)p2[0], (_Float16)p2[1], (_Float16)p3[0], (_Float16)p3[1]};
        }
    }
    preload_b<8>(wf0, lane, ba);
    layer_frag2<64, 128>(wf0, bb0v, af, lane, acc, ba, bb);
#pragma unroll
    for (int mt = 0; mt < 2; ++mt) store_d_tr<128>(lw + mt * REGION_HALFS, m, q, acc[mt], true);

    // ---- Layer 1 (128 -> 128) ----
    preload_b<8>(wf1, lane, ba);
    lds_fence();   // stores drained before transpose reads (same-wave data, no barrier needed)
    load_a_tr<128>(lw, lane_rd, af[0]);
    load_a_tr<128>(lw + REGION_HALFS, lane_rd, af[1]);
    lds_fence();
    __builtin_amdgcn_sched_barrier(0);   // rule 18: MFMA must not hoist above the wait
    layer_frag2<128, 128>(wf1, bb1v, af, lane, acc, ba, bb);
#pragma unroll
    for (int mt = 0; mt < 2; ++mt) store_d_tr<128>(lw + mt * REGION_HALFS, m, q, acc[mt], true);

    // ---- Layer 2 (128 -> 64) ----
    preload_b<4>(wf2, lane, ba);
    lds_fence();
    load_a_tr<128>(lw, lane_rd, af[0]);
    load_a_tr<128>(lw + REGION_HALFS, lane_rd, af[1]);
    lds_fence();
    __builtin_amdgcn_sched_barrier(0);
    layer_frag2<128, 64>(wf2, bb2v, af, lane, acc, ba, bb);
#pragma unroll
    for (int mt = 0; mt < 2; ++mt) store_d_tr<64>(lw + mt * REGION_HALFS, m, q, acc[mt], true);

    // ---- Layer 3 (64 -> 32): net stays in registers ----
    preload_b<2>(wf3, lane, ba);
    lds_fence();
    load_a_tr<64>(lw, lane_rd, af[0]);
    load_a_tr<64>(lw + REGION_HALFS, lane_rd, af[1]);

    // Prefetch epilogue u values so their latency hides behind layer-3 MFMAs.
    float ue[2][8];
#pragma unroll
    for (int mt = 0; mt < 2; ++mt)
#pragma unroll
        for (int ot = 0; ot < 2; ++ot)
#pragma unroll
            for (int r = 0; r < 4; ++r)
                ue[mt][ot * 4 + r] = u[(row0 + mt * 16 + q * 4 + r) * 64 + ot * 16 + m];

    lds_fence();
    __builtin_amdgcn_sched_barrier(0);
    layer_frag2<64, 32>(wf3, bb3v, af, lane, acc, ba, bb);   // acc[mt][0..1] = net tiles

    // ---- Epilogue: lane holds net[row=mt*16+q*4+r][col=ot*16+m] ----
    // Domain note: u in [1e-4, 1-1e-4] => lt in [-9.22, -1e-4]; every quantity is
    // finite in fp32, so the reference's nan_to_num is a no-op here (checks dropped).
#pragma unroll
    for (int ot = 0; ot < 2; ++ot) {
        const int d = ot * 16 + m;
        const float v1 = ev1[ot], v2 = ev2[ot], v4 = ev4[ot], v6 = ev6[ot];
        const float v5h = ev5h[ot];
        const float c3 = ec3[ot];
#pragma unroll
        for (int mt = 0; mt < 2; ++mt) {
#pragma unroll
            for (int r = 0; r < 4; ++r) {
                const size_t row = row0 + mt * 16 + q * 4 + r;
                const float net = acc[mt][ot][r];
                const float ud = ue[mt][ot * 4 + r];

                const float omu = 1.0f - ud;
                const float lt = __log2f(omu) * LN2_F;     // log(1-u) < 0
                const float x = -lt;                        // in (1e-4, 9.3)

                // E1 via Abramowitz-Stegun 5.1.53 (x<1) / 5.1.54 (x>=1)
                const float e1s = -__log2f(x) * LN2_F
                    + (-0.57721566f + x * (0.99999193f + x * (-0.24991055f
                    + x * (0.05519968f + x * (-0.00976004f + x * 0.00107857f)))));
                const float num = 0.2677737343f + x * (8.6347608925f + x * (18.0590169730f
                    + x * (8.5733287401f + x)));
                const float den = 3.9584969228f + x * (21.0996530827f + x * (25.6329561486f
                    + x * (9.5733223454f + x)));
                const float e1l = __expf(-x) * num * __builtin_amdgcn_rcpf(x * den);
                const float li = -((x < 1.0f) ? e1s : e1l); // _li(1-u)

                const float rl = __builtin_amdgcn_rcpf(lt); // 1/log_term
                const float phi = fmaf(v4, omu, v2) * rl
                                + (v5h * omu * (lt + 1.0f)) * rl * rl
                                + c3 * li;

                const float ud2 = ud * ud;
                const float ud4 = ud2 * ud2;
                const float p01 = ud4 * fmaf(-4.0f, ud, 5.0f);   // 5u^4 - 4u^5
                const float corr1 = p01 * (v1 + phi);
                const float d1 = ud - 1.0f;
                const float corr2 = v6 * ud * d1 * d1;           // u^3 - 2u^2 + u

                const float nt = fmaxf(net + corr1 + corr2, 0.0f);
                const float base = fmaf(-0.5f, ud2, 0.5f);       // (1-u^2)/2
                // base^(-nt) = exp2(-nt * log2(base)); v_exp_f32 is native exp2
                out[row * 32 + d] = __builtin_amdgcn_exp2f(-nt * __log2f(base));
            }
        }
    }
}

extern "C" void kernel_launch(void* const* d_in, const int* in_sizes, int n_in,
                              void* d_out, int out_size, void* d_ws, size_t ws_size,
                              hipStream_t stream) {
    const float* u    = (const float*)d_in[0];
    const float* W0   = (const float*)d_in[1];
    const float* b0   = (const float*)d_in[2];
    const float* W1   = (const float*)d_in[3];
    const float* b1   = (const float*)d_in[4];
    const float* W2   = (const float*)d_in[5];
    const float* b2   = (const float*)d_in[6];
    const float* W3   = (const float*)d_in[7];
    const float* b3   = (const float*)d_in[8];
    const float* var1 = (const float*)d_in[9];
    const float* var2 = (const float*)d_in[10];
    const float* var3 = (const float*)d_in[11];
    const float* var4 = (const float*)d_in[12];
    const float* var5 = (const float*)d_in[13];
    const float* var6 = (const float*)d_in[14];
    float* out = (float*)d_out;
    short* ws = (short*)d_ws;   // needs 69,632 B

    // Convert weights to f16 fragment layout (same work every launch).
    prep_weights<<<dim3(17), dim3(256), 0, stream>>>(W0, W1, W2, W3, ws);

    const int B = in_sizes[0] / 64;        // 262144 rows
    const int blocks = B / 128;            // 128 rows per block (32 per wave)
    mlp_phi_mfma<<<dim3(blocks), dim3(256), 0, stream>>>(
        u, b0, b1, b2, b3, ws,
        var1, var2, var3, var4, var5, var6, out);
}

// Round 4
// 173.107 us; speedup vs baseline: 1.0160x; 1.0160x over previous
//
#include <hip/hip_runtime.h>
#include <hip/hip_bf16.h>
#include <math.h>

#define LN2_F 0.69314718055994531f
#define REGION_HALFS 2048   // one 16-row m-tile, K<=128, subtiled for tr-read (4 KB)

typedef _Float16 half8 __attribute__((ext_vector_type(8)));  // MFMA A/B frag (4 VGPRs)
typedef _Float16 h4_t __attribute__((ext_vector_type(4)));   // b64 / tr-read payload
typedef __fp16 pk2_t __attribute__((ext_vector_type(2)));    // cvt_pkrtz native type
typedef __attribute__((ext_vector_type(4))) float f32x4;     // MFMA C/D frag
typedef __attribute__((ext_vector_type(8))) short short8;

// ---------------- weight prep: fp32 W -> f16 in B-fragment order ----------------
// B frag (mfma_f32_16x16x32_f16): lane l holds B[k = s*32 + (l>>4)*8 + j][n = ct*16 + (l&15)]
// ws layout (shorts): chunk cp = s*NT + ct at [cp*512 + lane*8 + j]. Layer bases:
// L0=0 (64x128,NT8), L1=8192 (128x128,NT8), L2=24576 (128x64,NT4), L3=32768 (64x32,NT2).
__global__ void prep_weights(const float* __restrict__ W0, const float* __restrict__ W1,
                             const float* __restrict__ W2, const float* __restrict__ W3,
                             short* __restrict__ ws) {
    int e = blockIdx.x * 256 + threadIdx.x;     // unit id, 4352 total
    const float* W; int N, NT, base, ul;
    if (e < 1024)      { W = W0; N = 128; NT = 8; base = 0;     ul = e; }
    else if (e < 3072) { W = W1; N = 128; NT = 8; base = 8192;  ul = e - 1024; }
    else if (e < 4096) { W = W2; N = 64;  NT = 4; base = 24576; ul = e - 3072; }
    else if (e < 4352) { W = W3; N = 32;  NT = 2; base = 32768; ul = e - 4096; }
    else return;
    const int cp = ul >> 6, lane = ul & 63;
    const int s = cp / NT, ct = cp % NT;
    const int k0 = s * 32 + (lane >> 4) * 8;
    const int n = ct * 16 + (lane & 15);
    union { half8 h; short8 s; } v;
#pragma unroll
    for (int j = 0; j < 8; ++j) v.h[j] = (_Float16)W[(size_t)(k0 + j) * N + n];
    *(short8*)(ws + base + cp * 512 + lane * 8) = v.s;
}

// ---------------- activation LDS tile (per 16-row m-tile) ----------------
// Element (row, k) at half-index (k>>2)*64 + (k&3)*16 + row  (VERIFIED round 3).
// Store: lane (q,m) writes D rows q*4..q*4+3 of col ct*16+m as ONE ds_write_b64 at
//   ct*256 + (m>>2)*64 + (m&3)*16 + q*4.
// Read: ds_read_b64_tr_b16 at byte addr base + s*1024 + q*256 + m*8 (+offset:128)
//   delivers A[m][s*32 + q*8 + j], j=0..7.

__device__ __forceinline__ void lds_fence() {
    asm volatile("s_waitcnt lgkmcnt(0)" ::: "memory");
}

__device__ __forceinline__ half8 tr_read_ks(const _Float16* region, unsigned lane_off, int s) {
    h4_t lo, hi;
    asm volatile("ds_read_b64_tr_b16 %0, %2\n\t"
                 "ds_read_b64_tr_b16 %1, %2 offset:128"
                 : "=&v"(lo), "=&v"(hi)
                 : "v"((unsigned)(uintptr_t)region + lane_off + (unsigned)(s * 1024))
                 : "memory");
    return __builtin_shufflevector(lo, hi, 0, 1, 2, 3, 4, 5, 6, 7);
}

__device__ __forceinline__ void store_tile(_Float16* __restrict__ region, int ct_global,
                                           int m, int q, f32x4 v, bool relu) {
    const int base = ct_global * 256 + (m >> 2) * 64 + (m & 3) * 16 + q * 4;
    float a0 = relu ? fmaxf(v[0], 0.0f) : v[0];
    float a1 = relu ? fmaxf(v[1], 0.0f) : v[1];
    float a2 = relu ? fmaxf(v[2], 0.0f) : v[2];
    float a3 = relu ? fmaxf(v[3], 0.0f) : v[3];
    pk2_t p0 = __builtin_amdgcn_cvt_pkrtz(a0, a1);
    pk2_t p1 = __builtin_amdgcn_cvt_pkrtz(a2, a3);
    h4_t h = {(_Float16)p0[0], (_Float16)p0[1], (_Float16)p1[0], (_Float16)p1[1]};
    *(h4_t*)(region + base) = h;       // ds_write_b64
}

// ---------------- cooperative column-split MLP ----------------
// Block = 4 waves processing 32 rows/chunk jointly. Wave w permanently holds the
// B-fragments for ITS columns of every layer in VGPRs (18 frags = 72 VGPRs):
//   L0/L1: col-tiles {2w, 2w+1}; L2: col-tile w; L3: col-tile w&1 (m-tile w>>1).
// Zero global weight loads in the chunk loop; activations pass via tr-LDS + barriers.
__global__ __launch_bounds__(256, 2) void mlp_phi_mfma(
    const float* __restrict__ u,
    const float* __restrict__ b0, const float* __restrict__ b1,
    const float* __restrict__ b2, const float* __restrict__ b3,
    const short* __restrict__ ws,
    const float* __restrict__ var1, const float* __restrict__ var2,
    const float* __restrict__ var3, const float* __restrict__ var4,
    const float* __restrict__ var5, const float* __restrict__ var6,
    float* __restrict__ out, int nchunks) {
    __shared__ __align__(16) _Float16 bufA[2 * REGION_HALFS];   // L0 out / L2 out
    __shared__ __align__(16) _Float16 bufB[2 * REGION_HALFS];   // L1 out
    const int t = threadIdx.x, lane = t & 63, wave = t >> 6;
    const int m = lane & 15, q = lane >> 4;
    const unsigned lane_rd = (unsigned)(q * 256 + m * 8);
    const int ct01 = 2 * wave;            // L0/L1 col-tile base (global ct = ct01+cl)
    const int mt3 = wave >> 1, ct3 = wave & 1;   // L3/epilogue assignment

    const half8* wf0 = (const half8*)(ws);
    const half8* wf1 = (const half8*)(ws + 8192);
    const half8* wf2 = (const half8*)(ws + 24576);
    const half8* wf3 = (const half8*)(ws + 32768);

    // ---- persistent weight fragments (loaded once per block lifetime) ----
    half8 w0f[2][2], w1f[4][2], w2f[4], w3f[2];
#pragma unroll
    for (int s = 0; s < 2; ++s)
#pragma unroll
        for (int cl = 0; cl < 2; ++cl)
            w0f[s][cl] = wf0[(s * 8 + ct01 + cl) * 64 + lane];
#pragma unroll
    for (int s = 0; s < 4; ++s)
#pragma unroll
        for (int cl = 0; cl < 2; ++cl)
            w1f[s][cl] = wf1[(s * 8 + ct01 + cl) * 64 + lane];
#pragma unroll
    for (int s = 0; s < 4; ++s) w2f[s] = wf2[(s * 4 + wave) * 64 + lane];
#pragma unroll
    for (int s = 0; s < 2; ++s) w3f[s] = wf3[(s * 2 + ct3) * 64 + lane];

    // ---- biases + epilogue constants (chunk-invariant) ----
    float bias0[2], bias1[2];
#pragma unroll
    for (int cl = 0; cl < 2; ++cl) {
        bias0[cl] = b0[(ct01 + cl) * 16 + m];
        bias1[cl] = b1[(ct01 + cl) * 16 + m];
    }
    const float bias2 = b2[wave * 16 + m];
    const float bias3 = b3[ct3 * 16 + m];

    const int d = ct3 * 16 + m;
    const float v1 = var1[d], v2 = var2[d], v4 = var4[d], v6 = var6[d];
    const float v5h = 0.5f * var5[d];
    const float c3 = var3[d] - v4 - v5h;

    f32x4 acc[2][2];

#pragma unroll 1
    for (int c = blockIdx.x; c < nchunks; c += gridDim.x) {
        const size_t row0 = (size_t)c * 32;

        // ---- Layer 0 (64 -> wave's 32 cols): A from global u (all waves, same rows) ----
#pragma unroll
        for (int mt = 0; mt < 2; ++mt) {
            const float* up = u + (row0 + mt * 16 + m) * 64;
            half8 a0[2];
#pragma unroll
            for (int s = 0; s < 2; ++s) {
                float4 v0a = *(const float4*)(up + s * 32 + q * 8);
                float4 v1a = *(const float4*)(up + s * 32 + q * 8 + 4);
                pk2_t p0 = __builtin_amdgcn_cvt_pkrtz(v0a.x, v0a.y);
                pk2_t p1 = __builtin_amdgcn_cvt_pkrtz(v0a.z, v0a.w);
                pk2_t p2 = __builtin_amdgcn_cvt_pkrtz(v1a.x, v1a.y);
                pk2_t p3 = __builtin_amdgcn_cvt_pkrtz(v1a.z, v1a.w);
                a0[s] = half8{(_Float16)p0[0], (_Float16)p0[1], (_Float16)p1[0], (_Float16)p1[1],
                              (_Float16)p2[0], (_Float16)p2[1], (_Float16)p3[0], (_Float16)p3[1]};
            }
#pragma unroll
            for (int cl = 0; cl < 2; ++cl) {
                float b = bias0[cl];
                acc[mt][cl] = f32x4{b, b, b, b};
            }
#pragma unroll
            for (int s = 0; s < 2; ++s)
#pragma unroll
                for (int cl = 0; cl < 2; ++cl)
                    acc[mt][cl] = __builtin_amdgcn_mfma_f32_16x16x32_f16(a0[s], w0f[s][cl],
                                                                         acc[mt][cl], 0, 0, 0);
#pragma unroll
            for (int cl = 0; cl < 2; ++cl)
                store_tile(bufA + mt * REGION_HALFS, ct01 + cl, m, q, acc[mt][cl], true);
        }
        __syncthreads();   // bufA complete (all 128 cols from 4 waves)

        // ---- Layer 1 (128 -> wave's 32 cols): A via tr-read of full bufA ----
#pragma unroll
        for (int mt = 0; mt < 2; ++mt) {
            half8 af[4];
#pragma unroll
            for (int s = 0; s < 4; ++s) af[s] = tr_read_ks(bufA + mt * REGION_HALFS, lane_rd, s);
            lds_fence();
            __builtin_amdgcn_sched_barrier(0);   // rule 18: MFMA must not hoist above wait
#pragma unroll
            for (int cl = 0; cl < 2; ++cl) {
                float b = bias1[cl];
                acc[mt][cl] = f32x4{b, b, b, b};
            }
#pragma unroll
            for (int s = 0; s < 4; ++s)
#pragma unroll
                for (int cl = 0; cl < 2; ++cl)
                    acc[mt][cl] = __builtin_amdgcn_mfma_f32_16x16x32_f16(af[s], w1f[s][cl],
                                                                         acc[mt][cl], 0, 0, 0);
#pragma unroll
            for (int cl = 0; cl < 2; ++cl)
                store_tile(bufB + mt * REGION_HALFS, ct01 + cl, m, q, acc[mt][cl], true);
        }
        __syncthreads();   // bufB complete; all bufA reads drained

        // ---- Layer 2 (128 -> wave's 16 cols): reads bufB, writes bufA cols [16w,16w+16) ----
        f32x4 acc2[2];
#pragma unroll
        for (int mt = 0; mt < 2; ++mt) {
            half8 af[4];
#pragma unroll
            for (int s = 0; s < 4; ++s) af[s] = tr_read_ks(bufB + mt * REGION_HALFS, lane_rd, s);
            lds_fence();
            __builtin_amdgcn_sched_barrier(0);
            acc2[mt] = f32x4{bias2, bias2, bias2, bias2};
#pragma unroll
            for (int s = 0; s < 4; ++s)
                acc2[mt] = __builtin_amdgcn_mfma_f32_16x16x32_f16(af[s], w2f[s], acc2[mt], 0, 0, 0);
            store_tile(bufA + mt * REGION_HALFS, wave, m, q, acc2[mt], true);
        }
        __syncthreads();   // bufA(64 cols) complete; bufB reads drained

        // ---- Layer 3 (64 -> 32): wave computes tile (mt3, ct3) only ----
        half8 a3[2];
#pragma unroll
        for (int s = 0; s < 2; ++s) a3[s] = tr_read_ks(bufA + mt3 * REGION_HALFS, lane_rd, s);

        // epilogue u loads issued here; latency hides under fence + MFMAs
        float ue[4];
#pragma unroll
        for (int r = 0; r < 4; ++r)
            ue[r] = u[(row0 + mt3 * 16 + q * 4 + r) * 64 + d];

        lds_fence();
        __builtin_amdgcn_sched_barrier(0);
        f32x4 acc3 = f32x4{bias3, bias3, bias3, bias3};
        acc3 = __builtin_amdgcn_mfma_f32_16x16x32_f16(a3[0], w3f[0], acc3, 0, 0, 0);
        acc3 = __builtin_amdgcn_mfma_f32_16x16x32_f16(a3[1], w3f[1], acc3, 0, 0, 0);

        // ---- Epilogue: lane holds net[row=mt3*16+q*4+r][col=d], r=0..3 ----
        // u in [1e-4, 1-1e-4] => all quantities finite in fp32 (nan_to_num is a no-op).
#pragma unroll
        for (int r = 0; r < 4; ++r) {
            const size_t row = row0 + mt3 * 16 + q * 4 + r;
            const float net = acc3[r];
            const float ud = ue[r];

            const float omu = 1.0f - ud;
            const float lt = __log2f(omu) * LN2_F;     // log(1-u) < 0
            const float x = -lt;                        // in (1e-4, 9.3)

            // E1 via Abramowitz-Stegun 5.1.53 (x<1) / 5.1.54 (x>=1)
            const float e1s = -__log2f(x) * LN2_F
                + (-0.57721566f + x * (0.99999193f + x * (-0.24991055f
                + x * (0.05519968f + x * (-0.00976004f + x * 0.00107857f)))));
            const float num = 0.2677737343f + x * (8.6347608925f + x * (18.0590169730f
                + x * (8.5733287401f + x)));
            const float den = 3.9584969228f + x * (21.0996530827f + x * (25.6329561486f
                + x * (9.5733223454f + x)));
            const float e1l = __expf(-x) * num * __builtin_amdgcn_rcpf(x * den);
            const float li = -((x < 1.0f) ? e1s : e1l); // _li(1-u)

            const float rl = __builtin_amdgcn_rcpf(lt); // 1/log_term
            const float phi = fmaf(v4, omu, v2) * rl
                            + (v5h * omu * (lt + 1.0f)) * rl * rl
                            + c3 * li;

            const float ud2 = ud * ud;
            const float ud4 = ud2 * ud2;
            const float p01 = ud4 * fmaf(-4.0f, ud, 5.0f);   // 5u^4 - 4u^5
            const float corr1 = p01 * (v1 + phi);
            const float d1 = ud - 1.0f;
            const float corr2 = v6 * ud * d1 * d1;           // u^3 - 2u^2 + u

            const float nt = fmaxf(net + corr1 + corr2, 0.0f);
            const float base = fmaf(-0.5f, ud2, 0.5f);       // (1-u^2)/2
            out[row * 32 + d] = __builtin_amdgcn_exp2f(-nt * __log2f(base));
        }
        __syncthreads();   // bufA L3-reads drained before next chunk's L0 stores
    }
}

extern "C" void kernel_launch(void* const* d_in, const int* in_sizes, int n_in,
                              void* d_out, int out_size, void* d_ws, size_t ws_size,
                              hipStream_t stream) {
    const float* u    = (const float*)d_in[0];
    const float* W0   = (const float*)d_in[1];
    const float* b0   = (const float*)d_in[2];
    const float* W1   = (const float*)d_in[3];
    const float* b1   = (const float*)d_in[4];
    const float* W2   = (const float*)d_in[5];
    const float* b2   = (const float*)d_in[6];
    const float* W3   = (const float*)d_in[7];
    const float* b3   = (const float*)d_in[8];
    const float* var1 = (const float*)d_in[9];
    const float* var2 = (const float*)d_in[10];
    const float* var3 = (const float*)d_in[11];
    const float* var4 = (const float*)d_in[12];
    const float* var5 = (const float*)d_in[13];
    const float* var6 = (const float*)d_in[14];
    float* out = (float*)d_out;
    short* ws = (short*)d_ws;   // needs 69,632 B

    // Convert weights to f16 fragment layout (same work every launch).
    prep_weights<<<dim3(17), dim3(256), 0, stream>>>(W0, W1, W2, W3, ws);

    const int B = in_sizes[0] / 64;        // 262144 rows
    const int nchunks = B / 32;            // 32 rows per block-chunk
    const int nblocks = nchunks < 1024 ? nchunks : 1024;   // persistent-ish, ~8 chunks each
    mlp_phi_mfma<<<dim3(nblocks), dim3(256), 0, stream>>>(
        u, b0, b1, b2, b3, ws,
        var1, var2, var3, var4, var5, var6, out, nchunks);
}

// Round 6
// 155.158 us; speedup vs baseline: 1.1335x; 1.1157x over previous
//
#include <hip/hip_runtime.h>
#include <hip/hip_bf16.h>
#include <math.h>

#define LN2_F 0.69314718055994531f
#define REGION_HALFS 2048   // one 16-row m-tile, K<=128, subtiled for tr-read (4 KB)

typedef _Float16 half8 __attribute__((ext_vector_type(8)));  // MFMA A/B frag (4 VGPRs)
typedef _Float16 h4_t __attribute__((ext_vector_type(4)));   // b64 / tr-read payload
typedef __fp16 pk2_t __attribute__((ext_vector_type(2)));    // cvt_pkrtz native type
typedef __attribute__((ext_vector_type(4))) float f32x4;     // MFMA C/D frag
typedef __attribute__((ext_vector_type(8))) short short8;

#define MFMA16(a, b, c) __builtin_amdgcn_mfma_f32_16x16x32_f16((a), (b), (c), 0, 0, 0)

// ---------------- weight prep: fp32 W -> f16 in B-fragment order ----------------
// B frag (mfma_f32_16x16x32_f16): lane l holds B[k = s*32 + (l>>4)*8 + j][n = ct*16 + (l&15)]
// ws layout (shorts): chunk cp = s*NT + ct at [cp*512 + lane*8 + j]. Layer bases:
// L0=0 (64x128,NT8), L1=8192 (128x128,NT8), L2=24576 (128x64,NT4), L3=32768 (64x32,NT2).
__global__ void prep_weights(const float* __restrict__ W0, const float* __restrict__ W1,
                             const float* __restrict__ W2, const float* __restrict__ W3,
                             short* __restrict__ ws) {
    int e = blockIdx.x * 256 + threadIdx.x;     // unit id, 4352 total
    const float* W; int N, NT, base, ul;
    if (e < 1024)      { W = W0; N = 128; NT = 8; base = 0;     ul = e; }
    else if (e < 3072) { W = W1; N = 128; NT = 8; base = 8192;  ul = e - 1024; }
    else if (e < 4096) { W = W2; N = 64;  NT = 4; base = 24576; ul = e - 3072; }
    else if (e < 4352) { W = W3; N = 32;  NT = 2; base = 32768; ul = e - 4096; }
    else return;
    const int cp = ul >> 6, lane = ul & 63;
    const int s = cp / NT, ct = cp % NT;
    const int k0 = s * 32 + (lane >> 4) * 8;
    const int n = ct * 16 + (lane & 15);
    union { half8 h; short8 s; } v;
#pragma unroll
    for (int j = 0; j < 8; ++j) v.h[j] = (_Float16)W[(size_t)(k0 + j) * N + n];
    *(short8*)(ws + base + cp * 512 + lane * 8) = v.s;
}

// ---------------- activation LDS tile (per 16-row m-tile) — VERIFIED r3/r4 ----------------
// Element (row, k) at half-index (k>>2)*64 + (k&3)*16 + row.
// Store: lane (q,m) writes D rows q*4..q*4+3 of col ct*16+m as ONE ds_write_b64 at
//   ct*256 + (m>>2)*64 + (m&3)*16 + q*4.
// Read: ds_read_b64_tr_b16 at byte addr base + s*1024 + q*256 + m*8 (+offset:128)
//   delivers A[m][s*32 + q*8 + j], j=0..7.

__device__ __forceinline__ void lds_fence() {
    asm volatile("s_waitcnt lgkmcnt(0)" ::: "memory");
}

__device__ __forceinline__ half8 tr_read_ks(const _Float16* region, unsigned lane_off, int s) {
    h4_t lo, hi;
    asm volatile("ds_read_b64_tr_b16 %0, %2\n\t"
                 "ds_read_b64_tr_b16 %1, %2 offset:128"
                 : "=&v"(lo), "=&v"(hi)
                 : "v"((unsigned)(uintptr_t)region + lane_off + (unsigned)(s * 1024))
                 : "memory");
    return __builtin_shufflevector(lo, hi, 0, 1, 2, 3, 4, 5, 6, 7);
}

__device__ __forceinline__ void store_tile(_Float16* __restrict__ region, int ct_global,
                                           int m, int q, f32x4 v) {
    const int base = ct_global * 256 + (m >> 2) * 64 + (m & 3) * 16 + q * 4;
    pk2_t p0 = __builtin_amdgcn_cvt_pkrtz(fmaxf(v[0], 0.0f), fmaxf(v[1], 0.0f));
    pk2_t p1 = __builtin_amdgcn_cvt_pkrtz(fmaxf(v[2], 0.0f), fmaxf(v[3], 0.0f));
    h4_t h = {(_Float16)p0[0], (_Float16)p0[1], (_Float16)p1[0], (_Float16)p1[1]};
    *(h4_t*)(region + base) = h;       // ds_write_b64
}

// ---------------- deep-pipelined layer: 2 m-tiles share every B fragment ----------------
// ba holds slice 0 on entry (preloaded by previous layer / prologue). All 8 loads of
// slice s+1 are issued before slice s's 16 MFMAs; the NEXT layer's slice 0 is issued
// into ba before this layer's final MFMA group, so its L2 latency hides under the
// LDS store/tr-read transition. Register cost: ba+bb = 64 VGPRs (needs (256,2) cap).
template <int K, int N, int NEXT_NT>
__device__ __forceinline__ void layer_pipe(const half8* __restrict__ wf,
                                           const half8* __restrict__ wf_next,
                                           const float* bias, const half8 (&af)[2][4],
                                           int lane, f32x4 (&acc)[2][8],
                                           half8 (&ba)[8], half8 (&bb)[8]) {
    constexpr int NK = K / 32, NT = N / 16;
    static_assert(NK == 2 || NK == 4, "");
#pragma unroll
    for (int ct = 0; ct < NT; ++ct) {
        const float b = bias[ct];
        acc[0][ct] = f32x4{b, b, b, b};
        acc[1][ct] = f32x4{b, b, b, b};
    }
#pragma unroll
    for (int ct = 0; ct < NT; ++ct) bb[ct] = wf[(NT + ct) * 64 + lane];   // slice 1 -> bb
#pragma unroll
    for (int ct = 0; ct < NT; ++ct) {                                     // slice 0 (ba)
        acc[0][ct] = MFMA16(af[0][0], ba[ct], acc[0][ct]);
        acc[1][ct] = MFMA16(af[1][0], ba[ct], acc[1][ct]);
    }
    if constexpr (NK == 4) {
#pragma unroll
        for (int ct = 0; ct < NT; ++ct) ba[ct] = wf[(2 * NT + ct) * 64 + lane];  // slice 2
#pragma unroll
        for (int ct = 0; ct < NT; ++ct) {                                 // slice 1 (bb)
            acc[0][ct] = MFMA16(af[0][1], bb[ct], acc[0][ct]);
            acc[1][ct] = MFMA16(af[1][1], bb[ct], acc[1][ct]);
        }
#pragma unroll
        for (int ct = 0; ct < NT; ++ct) bb[ct] = wf[(3 * NT + ct) * 64 + lane];  // slice 3
#pragma unroll
        for (int ct = 0; ct < NT; ++ct) {                                 // slice 2 (ba)
            acc[0][ct] = MFMA16(af[0][2], ba[ct], acc[0][ct]);
            acc[1][ct] = MFMA16(af[1][2], ba[ct], acc[1][ct]);
        }
        if constexpr (NEXT_NT > 0) {
#pragma unroll
            for (int ct = 0; ct < NEXT_NT; ++ct) ba[ct] = wf_next[ct * 64 + lane];
        }
#pragma unroll
        for (int ct = 0; ct < NT; ++ct) {                                 // slice 3 (bb)
            acc[0][ct] = MFMA16(af[0][3], bb[ct], acc[0][ct]);
            acc[1][ct] = MFMA16(af[1][3], bb[ct], acc[1][ct]);
        }
    } else {
        if constexpr (NEXT_NT > 0) {
#pragma unroll
            for (int ct = 0; ct < NEXT_NT; ++ct) ba[ct] = wf_next[ct * 64 + lane];
        }
#pragma unroll
        for (int ct = 0; ct < NT; ++ct) {                                 // slice 1 (bb)
            acc[0][ct] = MFMA16(af[0][1], bb[ct], acc[0][ct]);
            acc[1][ct] = MFMA16(af[1][1], bb[ct], acc[1][ct]);
        }
    }
}

__global__ __launch_bounds__(256, 2) void mlp_phi_mfma(
    const float* __restrict__ u,
    const float* __restrict__ b0, const float* __restrict__ b1,
    const float* __restrict__ b2, const float* __restrict__ b3,
    const short* __restrict__ ws,
    const float* __restrict__ var1, const float* __restrict__ var2,
    const float* __restrict__ var3, const float* __restrict__ var4,
    const float* __restrict__ var5, const float* __restrict__ var6,
    float* __restrict__ out) {
    // 4 waves/block, each wave owns 32 rows (two 16-row m-tiles) end-to-end.
    // No __syncthreads anywhere. LDS: 4 waves x 2 m-tile regions x 4 KB = 32 KB.
    __shared__ __align__(16) _Float16 lds[4 * 2 * REGION_HALFS];
    const int t = threadIdx.x, lane = t & 63, wave = t >> 6;
    const int m = lane & 15, q = lane >> 4;
    _Float16* lw = lds + wave * 2 * REGION_HALFS;
    const unsigned lane_rd = (unsigned)(q * 256 + m * 8);   // tr-read per-lane byte offset
    const size_t row0 = (size_t)blockIdx.x * 128 + wave * 32;

    const half8* wf0 = (const half8*)(ws);
    const half8* wf1 = (const half8*)(ws + 8192);
    const half8* wf2 = (const half8*)(ws + 24576);
    const half8* wf3 = (const half8*)(ws + 32768);

    half8 af[2][4];
    f32x4 acc[2][8];
    half8 ba[8], bb[8];

    // ---- Layer 0 A-frags from global u (HBM) + L0 slice-0 B preload, all in flight ----
#pragma unroll
    for (int ct = 0; ct < 8; ++ct) ba[ct] = wf0[ct * 64 + lane];
#pragma unroll
    for (int mt = 0; mt < 2; ++mt) {
        const float* up = u + (row0 + mt * 16 + m) * 64;
#pragma unroll
        for (int s = 0; s < 2; ++s) {
            float4 v0a = *(const float4*)(up + s * 32 + q * 8);
            float4 v1a = *(const float4*)(up + s * 32 + q * 8 + 4);
            pk2_t p0 = __builtin_amdgcn_cvt_pkrtz(v0a.x, v0a.y);
            pk2_t p1 = __builtin_amdgcn_cvt_pkrtz(v0a.z, v0a.w);
            pk2_t p2 = __builtin_amdgcn_cvt_pkrtz(v1a.x, v1a.y);
            pk2_t p3 = __builtin_amdgcn_cvt_pkrtz(v1a.z, v1a.w);
            af[mt][s] = half8{(_Float16)p0[0], (_Float16)p0[1], (_Float16)p1[0], (_Float16)p1[1],
                              (_Float16)p2[0], (_Float16)p2[1], (_Float16)p3[0], (_Float16)p3[1]};
        }
    }

    // ---- biases + epilogue constants (hoisted; reg budget is ample at (256,2)) ----
    float bb0v[8], bb1v[8], bb2v[4], bb3v[2];
#pragma unroll
    for (int ct = 0; ct < 8; ++ct) bb0v[ct] = b0[ct * 16 + m];
#pragma unroll
    for (int ct = 0; ct < 8; ++ct) bb1v[ct] = b1[ct * 16 + m];
#pragma unroll
    for (int ct = 0; ct < 4; ++ct) bb2v[ct] = b2[ct * 16 + m];
#pragma unroll
    for (int ct = 0; ct < 2; ++ct) bb3v[ct] = b3[ct * 16 + m];

    float ev1[2], ev2[2], ev4[2], ev6[2], ev5h[2], ec3[2];
#pragma unroll
    for (int ot = 0; ot < 2; ++ot) {
        const int d = ot * 16 + m;
        ev1[ot] = var1[d]; ev2[ot] = var2[d]; ev4[ot] = var4[d]; ev6[ot] = var6[d];
        ev5h[ot] = 0.5f * var5[d];
        ec3[ot] = var3[d] - ev4[ot] - ev5h[ot];     // li coefficient, hoisted
    }

    // ---- Layer 0 (64 -> 128); leaves L1 slice 0 in ba ----
    layer_pipe<64, 128, 8>(wf0, wf1, bb0v, af, lane, acc, ba, bb);
#pragma unroll
    for (int mt = 0; mt < 2; ++mt)
#pragma unroll
        for (int ct = 0; ct < 8; ++ct)
            store_tile(lw + mt * REGION_HALFS, ct, m, q, acc[mt][ct]);
    lds_fence();
#pragma unroll
    for (int mt = 0; mt < 2; ++mt)
#pragma unroll
        for (int s = 0; s < 4; ++s) af[mt][s] = tr_read_ks(lw + mt * REGION_HALFS, lane_rd, s);
    lds_fence();
    __builtin_amdgcn_sched_barrier(0);   // rule 18: MFMA must not hoist above the wait

    // ---- Layer 1 (128 -> 128); leaves L2 slice 0 in ba ----
    layer_pipe<128, 128, 4>(wf1, wf2, bb1v, af, lane, acc, ba, bb);
#pragma unroll
    for (int mt = 0; mt < 2; ++mt)
#pragma unroll
        for (int ct = 0; ct < 8; ++ct)
            store_tile(lw + mt * REGION_HALFS, ct, m, q, acc[mt][ct]);
    lds_fence();
#pragma unroll
    for (int mt = 0; mt < 2; ++mt)
#pragma unroll
        for (int s = 0; s < 4; ++s) af[mt][s] = tr_read_ks(lw + mt * REGION_HALFS, lane_rd, s);
    lds_fence();
    __builtin_amdgcn_sched_barrier(0);

    // ---- Layer 2 (128 -> 64); leaves L3 slice 0 in ba ----
    layer_pipe<128, 64, 2>(wf2, wf3, bb2v, af, lane, acc, ba, bb);
#pragma unroll
    for (int mt = 0; mt < 2; ++mt)
#pragma unroll
        for (int ct = 0; ct < 4; ++ct)
            store_tile(lw + mt * REGION_HALFS, ct, m, q, acc[mt][ct]);
    lds_fence();
#pragma unroll
    for (int mt = 0; mt < 2; ++mt)
#pragma unroll
        for (int s = 0; s < 2; ++s) af[mt][s] = tr_read_ks(lw + mt * REGION_HALFS, lane_rd, s);

    // Prefetch epilogue u values; latency hides behind the final fence + layer-3 MFMAs.
    float ue[2][8];
#pragma unroll
    for (int mt = 0; mt < 2; ++mt)
#pragma unroll
        for (int ot = 0; ot < 2; ++ot)
#pragma unroll
            for (int r = 0; r < 4; ++r)
                ue[mt][ot * 4 + r] = u[(row0 + mt * 16 + q * 4 + r) * 64 + ot * 16 + m];

    lds_fence();
    __builtin_amdgcn_sched_barrier(0);

    // ---- Layer 3 (64 -> 32): net stays in registers ----
    layer_pipe<64, 32, 0>(wf3, nullptr, bb3v, af, lane, acc, ba, bb);   // acc[mt][0..1]

    // ---- Epilogue: lane holds net[row=mt*16+q*4+r][col=ot*16+m] ----
    // Domain note: u in [1e-4, 1-1e-4] => lt in [-9.22, -1e-4]; every quantity is
    // finite in fp32, so the reference's nan_to_num is a no-op here (checks dropped).
#pragma unroll
    for (int ot = 0; ot < 2; ++ot) {
        const int d = ot * 16 + m;
        const float v1 = ev1[ot], v2 = ev2[ot], v4 = ev4[ot], v6 = ev6[ot];
        const float v5h = ev5h[ot];
        const float c3 = ec3[ot];
#pragma unroll
        for (int mt = 0; mt < 2; ++mt) {
#pragma unroll
            for (int r = 0; r < 4; ++r) {
                const size_t row = row0 + mt * 16 + q * 4 + r;
                const float net = acc[mt][ot][r];
                const float ud = ue[mt][ot * 4 + r];

                const float omu = 1.0f - ud;
                const float lt = __log2f(omu) * LN2_F;     // log(1-u) < 0
                const float x = -lt;                        // in (1e-4, 9.3)

                // E1 via Abramowitz-Stegun 5.1.53 (x<1) / 5.1.54 (x>=1)
                const float e1s = -__log2f(x) * LN2_F
                    + (-0.57721566f + x * (0.99999193f + x * (-0.24991055f
                    + x * (0.05519968f + x * (-0.00976004f + x * 0.00107857f)))));
                const float num = 0.2677737343f + x * (8.6347608925f + x * (18.0590169730f
                    + x * (8.5733287401f + x)));
                const float den = 3.9584969228f + x * (21.0996530827f + x * (25.6329561486f
                    + x * (9.5733223454f + x)));
                const float e1l = __expf(-x) * num * __builtin_amdgcn_rcpf(x * den);
                const float li = -((x < 1.0f) ? e1s : e1l); // _li(1-u)

                const float rl = __builtin_amdgcn_rcpf(lt); // 1/log_term
                const float phi = fmaf(v4, omu, v2) * rl
                                + (v5h * omu * (lt + 1.0f)) * rl * rl
                                + c3 * li;

                const float ud2 = ud * ud;
                const float ud4 = ud2 * ud2;
                const float p01 = ud4 * fmaf(-4.0f, ud, 5.0f);   // 5u^4 - 4u^5
                const float corr1 = p01 * (v1 + phi);
                const float d1 = ud - 1.0f;
                const float corr2 = v6 * ud * d1 * d1;           // u^3 - 2u^2 + u

                const float nt = fmaxf(net + corr1 + corr2, 0.0f);
                const float base = fmaf(-0.5f, ud2, 0.5f);       // (1-u^2)/2
                // base^(-nt) = exp2(-nt * log2(base)); v_exp_f32 is native exp2
                out[row * 32 + d] = __builtin_amdgcn_exp2f(-nt * __log2f(base));
            }
        }
    }
}

extern "C" void kernel_launch(void* const* d_in, const int* in_sizes, int n_in,
                              void* d_out, int out_size, void* d_ws, size_t ws_size,
                              hipStream_t stream) {
    const float* u    = (const float*)d_in[0];
    const float* W0   = (const float*)d_in[1];
    const float* b0   = (const float*)d_in[2];
    const float* W1   = (const float*)d_in[3];
    const float* b1   = (const float*)d_in[4];
    const float* W2   = (const float*)d_in[5];
    const float* b2   = (const float*)d_in[6];
    const float* W3   = (const float*)d_in[7];
    const float* b3   = (const float*)d_in[8];
    const float* var1 = (const float*)d_in[9];
    const float* var2 = (const float*)d_in[10];
    const float* var3 = (const float*)d_in[11];
    const float* var4 = (const float*)d_in[12];
    const float* var5 = (const float*)d_in[13];
    const float* var6 = (const float*)d_in[14];
    float* out = (float*)d_out;
    short* ws = (short*)d_ws;   // needs 69,632 B

    // Convert weights to f16 fragment layout (same work every launch).
    prep_weights<<<dim3(17), dim3(256), 0, stream>>>(W0, W1, W2, W3, ws);

    const int B = in_sizes[0] / 64;        // 262144 rows
    const int blocks = B / 128;            // 128 rows per block (32 per wave)
    mlp_phi_mfma<<<dim3(blocks), dim3(256), 0, stream>>>(
        u, b0, b1, b2, b3, ws,
        var1, var2, var3, var4, var5, var6, out);
}

// Round 7
// 150.149 us; speedup vs baseline: 1.1713x; 1.0334x over previous
//
#include <hip/hip_runtime.h>
#include <hip/hip_bf16.h>
#include <math.h>

#define LN2_F 0.69314718055994531f
#define REGION_HALFS 2048   // one 16-row m-tile, K<=128, subtiled for tr-read (4 KB)

typedef _Float16 half8 __attribute__((ext_vector_type(8)));  // MFMA A/B frag (4 VGPRs)
typedef _Float16 h4_t __attribute__((ext_vector_type(4)));   // b64 / tr-read payload
typedef __fp16 pk2_t __attribute__((ext_vector_type(2)));    // cvt_pkrtz native type
typedef __attribute__((ext_vector_type(4))) float f32x4;     // MFMA C/D frag
typedef __attribute__((ext_vector_type(8))) short short8;

#define MFMA16(a, b, c) __builtin_amdgcn_mfma_f32_16x16x32_f16((a), (b), (c), 0, 0, 0)

// ---------------- weight prep: fp32 W -> f16 in B-fragment order ----------------
// B frag (mfma_f32_16x16x32_f16): lane l holds B[k = s*32 + (l>>4)*8 + j][n = ct*16 + (l&15)]
// ws layout (shorts): chunk cp = s*NT + ct at [cp*512 + lane*8 + j]. Layer bases:
// L0=0 (64x128,NT8), L1=8192 (128x128,NT8), L2=24576 (128x64,NT4), L3=32768 (64x32,NT2).
__global__ void prep_weights(const float* __restrict__ W0, const float* __restrict__ W1,
                             const float* __restrict__ W2, const float* __restrict__ W3,
                             short* __restrict__ ws) {
    int e = blockIdx.x * 256 + threadIdx.x;     // unit id, 4352 total
    const float* W; int N, NT, base, ul;
    if (e < 1024)      { W = W0; N = 128; NT = 8; base = 0;     ul = e; }
    else if (e < 3072) { W = W1; N = 128; NT = 8; base = 8192;  ul = e - 1024; }
    else if (e < 4096) { W = W2; N = 64;  NT = 4; base = 24576; ul = e - 3072; }
    else if (e < 4352) { W = W3; N = 32;  NT = 2; base = 32768; ul = e - 4096; }
    else return;
    const int cp = ul >> 6, lane = ul & 63;
    const int s = cp / NT, ct = cp % NT;
    const int k0 = s * 32 + (lane >> 4) * 8;
    const int n = ct * 16 + (lane & 15);
    union { half8 h; short8 s; } v;
#pragma unroll
    for (int j = 0; j < 8; ++j) v.h[j] = (_Float16)W[(size_t)(k0 + j) * N + n];
    *(short8*)(ws + base + cp * 512 + lane * 8) = v.s;
}

// ---------------- activation LDS tile (per 16-row m-tile) — VERIFIED r3/r4/r6 ----------------
// Element (row, k) at half-index (k>>2)*64 + (k&3)*16 + row.
// Store: lane (q,m) writes D rows q*4..q*4+3 of col ct*16+m as ONE ds_write_b64 at
//   ct*256 + (m>>2)*64 + (m&3)*16 + q*4.
// Read: ds_read_b64_tr_b16 at byte addr base + s*1024 + q*256 + m*8 (+offset:128)
//   delivers A[m][s*32 + q*8 + j], j=0..7.

__device__ __forceinline__ void lds_fence() {
    asm volatile("s_waitcnt lgkmcnt(0)" ::: "memory");
}

__device__ __forceinline__ half8 tr_read_ks(const _Float16* region, unsigned lane_off, int s) {
    h4_t lo, hi;
    asm volatile("ds_read_b64_tr_b16 %0, %2\n\t"
                 "ds_read_b64_tr_b16 %1, %2 offset:128"
                 : "=&v"(lo), "=&v"(hi)
                 : "v"((unsigned)(uintptr_t)region + lane_off + (unsigned)(s * 1024))
                 : "memory");
    return __builtin_shufflevector(lo, hi, 0, 1, 2, 3, 4, 5, 6, 7);
}

__device__ __forceinline__ void store_tile(_Float16* __restrict__ region, int ct_global,
                                           int m, int q, f32x4 v) {
    const int base = ct_global * 256 + (m >> 2) * 64 + (m & 3) * 16 + q * 4;
    pk2_t p0 = __builtin_amdgcn_cvt_pkrtz(fmaxf(v[0], 0.0f), fmaxf(v[1], 0.0f));
    pk2_t p1 = __builtin_amdgcn_cvt_pkrtz(fmaxf(v[2], 0.0f), fmaxf(v[3], 0.0f));
    h4_t h = {(_Float16)p0[0], (_Float16)p0[1], (_Float16)p1[0], (_Float16)p1[1]};
    *(h4_t*)(region + base) = h;       // ds_write_b64
}

// ---------------- half-layer: NC col-tiles (<=4), 2 m-tiles share every B fragment ----------
// acc[2][NC] is the ONLY live accumulator (32 AGPR max) — the register diet that buys
// 4 blocks/CU. Biases loaded just-in-time (L2-hot). B frags loaded per-slice (the
// compiler schedules these fine; explicit double-buffering was a no-op — r6).
template <int NK, int NT, int NC>
__device__ __forceinline__ void layer_half(const half8* __restrict__ wf,
                                           const float* __restrict__ bias, int ct0,
                                           const half8 (&af)[2][4], int lane, int m,
                                           f32x4 (&acc)[2][4]) {
#pragma unroll
    for (int c = 0; c < NC; ++c) {
        const float b = bias[(ct0 + c) * 16 + m];
        acc[0][c] = f32x4{b, b, b, b};
        acc[1][c] = f32x4{b, b, b, b};
    }
#pragma unroll
    for (int s = 0; s < NK; ++s) {
        half8 bf[4];
#pragma unroll
        for (int c = 0; c < NC; ++c) bf[c] = wf[(s * NT + ct0 + c) * 64 + lane];
#pragma unroll
        for (int c = 0; c < NC; ++c) {
            acc[0][c] = MFMA16(af[0][s], bf[c], acc[0][c]);
            acc[1][c] = MFMA16(af[1][s], bf[c], acc[1][c]);
        }
    }
}

__global__ __launch_bounds__(256, 4) void mlp_phi_mfma(
    const float* __restrict__ u,
    const float* __restrict__ b0, const float* __restrict__ b1,
    const float* __restrict__ b2, const float* __restrict__ b3,
    const short* __restrict__ ws,
    const float* __restrict__ var1, const float* __restrict__ var2,
    const float* __restrict__ var3, const float* __restrict__ var4,
    const float* __restrict__ var5, const float* __restrict__ var6,
    float* __restrict__ out) {
    // 4 waves/block, each wave owns 32 rows (two 16-row m-tiles) end-to-end.
    // No __syncthreads anywhere. LDS: 4 waves x 2 m-tile regions x 4 KB = 32 KB
    // -> 4 blocks/CU by LDS (128 KB); target <=128 unified regs for 4 blocks by regs too.
    __shared__ __align__(16) _Float16 lds[4 * 2 * REGION_HALFS];
    const int t = threadIdx.x, lane = t & 63, wave = t >> 6;
    const int m = lane & 15, q = lane >> 4;
    _Float16* lw = lds + wave * 2 * REGION_HALFS;
    const unsigned lane_rd = (unsigned)(q * 256 + m * 8);   // tr-read per-lane byte offset
    const size_t row0 = (size_t)blockIdx.x * 128 + wave * 32;

    const half8* wf0 = (const half8*)(ws);
    const half8* wf1 = (const half8*)(ws + 8192);
    const half8* wf2 = (const half8*)(ws + 24576);
    const half8* wf3 = (const half8*)(ws + 32768);

    half8 af[2][4];
    f32x4 acc[2][4];

    // ---- Layer 0 A-frags straight from global u (HBM), cvt_pkrtz fp32->f16 ----
#pragma unroll
    for (int mt = 0; mt < 2; ++mt) {
        const float* up = u + (row0 + mt * 16 + m) * 64;
#pragma unroll
        for (int s = 0; s < 2; ++s) {
            float4 v0a = *(const float4*)(up + s * 32 + q * 8);
            float4 v1a = *(const float4*)(up + s * 32 + q * 8 + 4);
            pk2_t p0 = __builtin_amdgcn_cvt_pkrtz(v0a.x, v0a.y);
            pk2_t p1 = __builtin_amdgcn_cvt_pkrtz(v0a.z, v0a.w);
            pk2_t p2 = __builtin_amdgcn_cvt_pkrtz(v1a.x, v1a.y);
            pk2_t p3 = __builtin_amdgcn_cvt_pkrtz(v1a.z, v1a.w);
            af[mt][s] = half8{(_Float16)p0[0], (_Float16)p0[1], (_Float16)p1[0], (_Float16)p1[1],
                              (_Float16)p2[0], (_Float16)p2[1], (_Float16)p3[0], (_Float16)p3[1]};
        }
    }

    // ---- Layer 0 (64 -> 128) in two 64-col halves ----
#pragma unroll
    for (int h = 0; h < 2; ++h) {
        layer_half<2, 8, 4>(wf0, b0, h * 4, af, lane, m, acc);
#pragma unroll
        for (int mt = 0; mt < 2; ++mt)
#pragma unroll
            for (int c = 0; c < 4; ++c)
                store_tile(lw + mt * REGION_HALFS, h * 4 + c, m, q, acc[mt][c]);
    }
    lds_fence();
#pragma unroll
    for (int mt = 0; mt < 2; ++mt)
#pragma unroll
        for (int s = 0; s < 4; ++s) af[mt][s] = tr_read_ks(lw + mt * REGION_HALFS, lane_rd, s);
    lds_fence();
    __builtin_amdgcn_sched_barrier(0);   // rule 18: MFMA must not hoist above the wait

    // ---- Layer 1 (128 -> 128) in two 64-col halves ----
#pragma unroll
    for (int h = 0; h < 2; ++h) {
        layer_half<4, 8, 4>(wf1, b1, h * 4, af, lane, m, acc);
#pragma unroll
        for (int mt = 0; mt < 2; ++mt)
#pragma unroll
            for (int c = 0; c < 4; ++c)
                store_tile(lw + mt * REGION_HALFS, h * 4 + c, m, q, acc[mt][c]);
    }
    lds_fence();
#pragma unroll
    for (int mt = 0; mt < 2; ++mt)
#pragma unroll
        for (int s = 0; s < 4; ++s) af[mt][s] = tr_read_ks(lw + mt * REGION_HALFS, lane_rd, s);
    lds_fence();
    __builtin_amdgcn_sched_barrier(0);

    // ---- Layer 2 (128 -> 64): single half (NT=4) ----
    layer_half<4, 4, 4>(wf2, b2, 0, af, lane, m, acc);
#pragma unroll
    for (int mt = 0; mt < 2; ++mt)
#pragma unroll
        for (int c = 0; c < 4; ++c)
            store_tile(lw + mt * REGION_HALFS, c, m, q, acc[mt][c]);
    lds_fence();
#pragma unroll
    for (int mt = 0; mt < 2; ++mt)
#pragma unroll
        for (int s = 0; s < 2; ++s) af[mt][s] = tr_read_ks(lw + mt * REGION_HALFS, lane_rd, s);
    lds_fence();
    __builtin_amdgcn_sched_barrier(0);

    // ---- Layer 3 (64 -> 32): net stays in registers (acc[mt][0..1]) ----
    layer_half<2, 2, 2>(wf3, b3, 0, af, lane, m, acc);

    // ---- Epilogue: lane holds net[row=mt*16+q*4+r][col=ot*16+m] ----
    // Constants + u re-loads happen here (L2-hot, ~1 KB) instead of whole-kernel
    // register residency; 16 waves/CU of TLP hide their latency.
    // Domain note: u in [1e-4, 1-1e-4] => lt in [-9.22, -1e-4]; every quantity is
    // finite in fp32, so the reference's nan_to_num is a no-op here (checks dropped).
#pragma unroll
    for (int ot = 0; ot < 2; ++ot) {
        const int d = ot * 16 + m;
        const float v1 = var1[d], v2 = var2[d], v4 = var4[d], v6 = var6[d];
        const float v5h = 0.5f * var5[d];
        const float c3 = var3[d] - v4 - v5h;     // li coefficient
#pragma unroll
        for (int mt = 0; mt < 2; ++mt) {
            float ue[4];
#pragma unroll
            for (int r = 0; r < 4; ++r)
                ue[r] = u[(row0 + mt * 16 + q * 4 + r) * 64 + d];
#pragma unroll
            for (int r = 0; r < 4; ++r) {
                const size_t row = row0 + mt * 16 + q * 4 + r;
                const float net = acc[mt][ot][r];
                const float ud = ue[r];

                const float omu = 1.0f - ud;
                const float lt = __log2f(omu) * LN2_F;     // log(1-u) < 0
                const float x = -lt;                        // in (1e-4, 9.3)

                // E1 via Abramowitz-Stegun 5.1.53 (x<1) / 5.1.54 (x>=1)
                const float e1s = -__log2f(x) * LN2_F
                    + (-0.57721566f + x * (0.99999193f + x * (-0.24991055f
                    + x * (0.05519968f + x * (-0.00976004f + x * 0.00107857f)))));
                const float num = 0.2677737343f + x * (8.6347608925f + x * (18.0590169730f
                    + x * (8.5733287401f + x)));
                const float den = 3.9584969228f + x * (21.0996530827f + x * (25.6329561486f
                    + x * (9.5733223454f + x)));
                const float e1l = __expf(-x) * num * __builtin_amdgcn_rcpf(x * den);
                const float li = -((x < 1.0f) ? e1s : e1l); // _li(1-u)

                const float rl = __builtin_amdgcn_rcpf(lt); // 1/log_term
                const float phi = fmaf(v4, omu, v2) * rl
                                + (v5h * omu * (lt + 1.0f)) * rl * rl
                                + c3 * li;

                const float ud2 = ud * ud;
                const float ud4 = ud2 * ud2;
                const float p01 = ud4 * fmaf(-4.0f, ud, 5.0f);   // 5u^4 - 4u^5
                const float corr1 = p01 * (v1 + phi);
                const float d1 = ud - 1.0f;
                const float corr2 = v6 * ud * d1 * d1;           // u^3 - 2u^2 + u

                const float nt = fmaxf(net + corr1 + corr2, 0.0f);
                const float base = fmaf(-0.5f, ud2, 0.5f);       // (1-u^2)/2
                // base^(-nt) = exp2(-nt * log2(base)); v_exp_f32 is native exp2
                out[row * 32 + d] = __builtin_amdgcn_exp2f(-nt * __log2f(base));
            }
        }
    }
}

extern "C" void kernel_launch(void* const* d_in, const int* in_sizes, int n_in,
                              void* d_out, int out_size, void* d_ws, size_t ws_size,
                              hipStream_t stream) {
    const float* u    = (const float*)d_in[0];
    const float* W0   = (const float*)d_in[1];
    const float* b0   = (const float*)d_in[2];
    const float* W1   = (const float*)d_in[3];
    const float* b1   = (const float*)d_in[4];
    const float* W2   = (const float*)d_in[5];
    const float* b2   = (const float*)d_in[6];
    const float* W3   = (const float*)d_in[7];
    const float* b3   = (const float*)d_in[8];
    const float* var1 = (const float*)d_in[9];
    const float* var2 = (const float*)d_in[10];
    const float* var3 = (const float*)d_in[11];
    const float* var4 = (const float*)d_in[12];
    const float* var5 = (const float*)d_in[13];
    const float* var6 = (const float*)d_in[14];
    float* out = (float*)d_out;
    short* ws = (short*)d_ws;   // needs 69,632 B

    // Convert weights to f16 fragment layout (same work every launch).
    prep_weights<<<dim3(17), dim3(256), 0, stream>>>(W0, W1, W2, W3, ws);

    const int B = in_sizes[0] / 64;        // 262144 rows
    const int blocks = B / 128;            // 128 rows per block (32 per wave)
    mlp_phi_mfma<<<dim3(blocks), dim3(256), 0, stream>>>(
        u, b0, b1, b2, b3, ws,
        var1, var2, var3, var4, var5, var6, out);
}